// Round 2
// baseline (147.344 us; speedup 1.0000x reference)
//
#include <hip/hip_runtime.h>
#include <math.h>

// Problem constants (SelectiveSSM)
#define BATCH   2
#define SEQLEN  512
#define DI      4096      // d_inner
#define DS      16        // d_state
#define RDT     128       // dt_rank
#define RTOT    160       // dt_rank + 2*d_state
#define BL      1024      // BATCH*SEQLEN rows

#define LOG2E 1.44269504088896340736f
#define LN2   0.69314718055994530942f

typedef __bf16 bf16;
typedef bf16  bf16x8 __attribute__((ext_vector_type(8)));
typedef float f32x4  __attribute__((ext_vector_type(4)));

__device__ __forceinline__ bf16x8 cvt8(const float4 a, const float4 b) {
  bf16x8 r;
  r[0] = (bf16)a.x; r[1] = (bf16)a.y; r[2] = (bf16)a.z; r[3] = (bf16)a.w;
  r[4] = (bf16)b.x; r[5] = (bf16)b.y; r[6] = (bf16)b.z; r[7] = (bf16)b.w;
  return r;
}

__device__ __forceinline__ bf16x8 cvt8s(const float4 a, const float4 b, const float s) {
  bf16x8 r;
  r[0] = (bf16)(s * a.x); r[1] = (bf16)(s * a.y); r[2] = (bf16)(s * a.z); r[3] = (bf16)(s * a.w);
  r[4] = (bf16)(s * b.x); r[5] = (bf16)(s * b.y); r[6] = (bf16)(s * b.z); r[7] = (bf16)(s * b.w);
  return r;
}

// ---------------------------------------------------------------------------
// Zero the 640 KB xp accumulator. 160 blocks x 256 threads x float4 = 640 KB.
// (A kernel, NOT hipMemsetAsync — memset-node capture is a graph tripwire.)
// ---------------------------------------------------------------------------
__global__ __launch_bounds__(256) void zero_xp(float* __restrict__ xp) {
  const int i = blockIdx.x * 256 + threadIdx.x;
  *(float4*)&xp[4 * (size_t)i] = make_float4(0.f, 0.f, 0.f, 0.f);
}

// ---------------------------------------------------------------------------
// GEMM1 fused: xp[row][col] += x[row, kslice] . W[col, kslice]
// grid (64 M-tiles of 16 rows, 8 k-splits) = 512 blocks, 2 blocks/CU.
// The 4 waves split the 512-wide K slice (128 each), accumulate 16x160 via
// MFMA, reduce across waves in LDS, then one fp32 atomicAdd per output into
// the 640 KB xp buffer. W is read fp32 and cast to bf16 inline.
// ---------------------------------------------------------------------------
#define MT    16
#define KS    8
#define LPAD  168

__global__ __launch_bounds__(256, 2) void gemm_xp(const float* __restrict__ x,
                                                  const float* __restrict__ W,
                                                  float* __restrict__ xp) {
  __shared__ float Lred[4][MT * LPAD];   // 43,008 B
  const int tid = threadIdx.x;
  const int w = tid >> 6;
  const int lane = tid & 63;
  const int m = lane & 15;
  const int q = lane >> 4;
  const int row0 = blockIdx.x * MT;
  const int k0 = blockIdx.y * (DI / KS) + w * 128;

  f32x4 acc[10] = {};
  const float* ap = x + (size_t)(row0 + m) * DI + k0 + 8 * q;
  const float* wp = W + (size_t)m * DI + k0 + 8 * q;

#pragma unroll
  for (int kk = 0; kk < 128; kk += 32) {
    float4 a0 = *(const float4*)(ap + kk);
    float4 a1 = *(const float4*)(ap + kk + 4);
    bf16x8 af = cvt8(a0, a1);
#pragma unroll
    for (int nt = 0; nt < 10; ++nt) {
      const float* wq = wp + (size_t)nt * 16 * DI + kk;
      float4 b0 = *(const float4*)(wq);
      float4 b1 = *(const float4*)(wq + 4);
      acc[nt] = __builtin_amdgcn_mfma_f32_16x16x32_bf16(af, cvt8(b0, b1), acc[nt], 0, 0, 0);
    }
  }

  // C/D layout: col = m (N dim), row = 4q + r (M dim). Stage to LDS.
#pragma unroll
  for (int nt = 0; nt < 10; ++nt)
#pragma unroll
    for (int r = 0; r < 4; ++r)
      Lred[w][(4 * q + r) * LPAD + nt * 16 + m] = acc[nt][r];
  __syncthreads();

  // Cross-wave reduce (4-way) + device atomic accumulate across k-splits.
#pragma unroll
  for (int i = 0; i < 10; ++i) {
    const int o = i * 256 + tid;           // 0..2559 over 16x160 outputs
    const int row = o / 160;
    const int col = o - row * 160;
    const int a = row * LPAD + col;
    const float s = Lred[0][a] + Lred[1][a] + Lred[2][a] + Lred[3][a];
    unsafeAtomicAdd(&xp[(size_t)(row0 + row) * RTOT + col], s);
  }
}

// ---------------------------------------------------------------------------
// 16-lane (DPP row) sum reduction on the VALU pipe. Result valid in lane 15
// of each 16-lane row.
// ---------------------------------------------------------------------------
__device__ __forceinline__ float row16_reduce_add(float p) {
  p += __int_as_float(__builtin_amdgcn_update_dpp(
      0, __float_as_int(p), 0x111, 0xf, 0xf, true));  // row_shr:1
  p += __int_as_float(__builtin_amdgcn_update_dpp(
      0, __float_as_int(p), 0x112, 0xf, 0xf, true));  // row_shr:2
  p += __int_as_float(__builtin_amdgcn_update_dpp(
      0, __float_as_int(p), 0x114, 0xf, 0xf, true));  // row_shr:4
  p += __int_as_float(__builtin_amdgcn_update_dpp(
      0, __float_as_int(p), 0x118, 0xf, 0xf, true));  // row_shr:8
  return p;
}

// ---------------------------------------------------------------------------
// Fused GEMM2 + selective scan.
// Reads xp fp32 directly: cols 0..127 = dt_in (cast to bf16 at MFMA use),
// cols 128..159 = B,C. dtw cast inline, pre-scaled by log2(e) so softplus
// and the per-step exponential run in exp2/log2 domain.
// ---------------------------------------------------------------------------
#define TC  64
#define TCP 68
#define NCH (SEQLEN / TC)

__global__ __launch_bounds__(256, 2) void scan_fused(const float* __restrict__ x,
                                                     const float* __restrict__ A_log,
                                                     const float* __restrict__ Dvec,
                                                     const float* __restrict__ xp,
                                                     const float* __restrict__ dtw,
                                                     const float* __restrict__ dtb,
                                                     float* __restrict__ out) {
  __shared__ __align__(16) float dtS[16][TCP];  // [dc][t]
  __shared__ __align__(16) float xS[16][TCP];   // [dc][t]
  __shared__ __align__(16) float BS[16][TCP];   // [n][t]
  __shared__ __align__(16) float CS[16][TCP];   // [n][t]
  __shared__ __align__(16) float yS[TC][16];    // [t][dc]

  const int bid = blockIdx.x;         // 0..511
  const int b = bid >> 8;
  const int d0 = (bid & 255) * 16;
  const int tid = threadIdx.x;
  const int n = tid & 15;             // state (scan) / MFMA m
  const int dc = tid >> 4;            // channel (scan)
  const int d = d0 + dc;
  const int w = tid >> 6;             // wave id (MFMA staging)
  const int m = tid & 15;
  const int q = (tid >> 4) & 3;

  const float A2 = -LOG2E * __expf(A_log[d * DS + n]);   // exp2-folded A
  const float Dd = Dvec[d];
  const float bias2 = dtb[d0 + m] * LOG2E;

  // dtw B-fragments: chunk-invariant, scaled by log2e, cast inline
  bf16x8 bfragW[4];
#pragma unroll
  for (int k = 0; k < 4; ++k) {
    const float* p = dtw + (size_t)(d0 + m) * RDT + 32 * k + 8 * q;
    float4 w0 = *(const float4*)p;
    float4 w1 = *(const float4*)(p + 4);
    bfragW[k] = cvt8s(w0, w1, LOG2E);
  }

  // loader mapping for x/B/C/y: thread -> row lt (0..63), 4-elem slice lf
  const int lt = tid >> 2;
  const int lf = (tid & 3) * 4;
  const int rowbase = b * SEQLEN;

  // prefetch chunk 0 (raw fp32 for the dt MFMA A operand; cvt at use)
  float4 a0[4], a1[4];
  float4 rx, rB, rC;
  {
    const int arow = rowbase + 16 * w + m;
#pragma unroll
    for (int k = 0; k < 4; ++k) {
      const float* p = xp + (size_t)arow * RTOT + 32 * k + 8 * q;
      a0[k] = *(const float4*)p;
      a1[k] = *(const float4*)(p + 4);
    }
    const int row = rowbase + lt;
    rx = *(const float4*)&x[(size_t)row * DI + d0 + lf];
    rB = *(const float4*)&xp[(size_t)row * RTOT + RDT + lf];
    rC = *(const float4*)&xp[(size_t)row * RTOT + RDT + 16 + lf];
  }

  float h = 0.f;

  for (int c = 0; c < NCH; ++c) {
    if (c > 0) __syncthreads();   // prev compute (LDS reads + yS writes) done

    // ---- stage dt via MFMA + softplus (log2 domain) ----
    {
      f32x4 acc = {};
#pragma unroll
      for (int k = 0; k < 4; ++k)
        acc = __builtin_amdgcn_mfma_f32_16x16x32_bf16(cvt8(a0[k], a1[k]), bfragW[k], acc, 0, 0, 0);
      // D layout: col m = channel, row 4q+r = timestep within 16-row tile
#pragma unroll
      for (int r = 0; r < 4; ++r) {
        const float z2 = acc[r] + bias2;             // = z * log2(e)
        dtS[m][16 * w + 4 * q + r] = (z2 > 28.854f) ? z2 * LN2
                                   : LN2 * __log2f(1.f + exp2f(z2));
      }
    }
    // ---- stage x, B, C (transposed) ----
    {
      const float rxa[4] = {rx.x, rx.y, rx.z, rx.w};
      const float rBa[4] = {rB.x, rB.y, rB.z, rB.w};
      const float rCa[4] = {rC.x, rC.y, rC.z, rC.w};
#pragma unroll
      for (int j = 0; j < 4; ++j) {
        xS[lf + j][lt] = rxa[j];
        BS[lf + j][lt] = rBa[j];
        CS[lf + j][lt] = rCa[j];
      }
    }
    // ---- store previous chunk's y (different LDS region; reads pre-barrier2)
    if (c > 0) {
      const int prow = rowbase + (c - 1) * TC + lt;
      float4 yv = *(const float4*)&yS[lt][lf];
      *(float4*)&out[(size_t)prow * DI + d0 + lf] = yv;
    }

    __syncthreads();              // tiles ready; yS reads done

    // ---- prefetch next chunk ----
    if (c < NCH - 1) {
      const int arow = rowbase + (c + 1) * TC + 16 * w + m;
#pragma unroll
      for (int k = 0; k < 4; ++k) {
        const float* p = xp + (size_t)arow * RTOT + 32 * k + 8 * q;
        a0[k] = *(const float4*)p;
        a1[k] = *(const float4*)(p + 4);
      }
      const int row = rowbase + (c + 1) * TC + lt;
      rx = *(const float4*)&x[(size_t)row * DI + d0 + lf];
      rB = *(const float4*)&xp[(size_t)row * RTOT + RDT + lf];
      rC = *(const float4*)&xp[(size_t)row * RTOT + RDT + 16 + lf];
    }

    // ---- 64 steps: 8 groups of 8, fully unrolled so the scheduler can
    //      overlap group g+1's LDS reads with group g's DPP reduce ----
#pragma unroll
    for (int g = 0; g < 8; ++g) {
      const int t0 = 8 * g;
      const float4 dv0 = *(const float4*)&dtS[dc][t0];
      const float4 dv1 = *(const float4*)&dtS[dc][t0 + 4];
      const float4 xv0 = *(const float4*)&xS[dc][t0];
      const float4 xv1 = *(const float4*)&xS[dc][t0 + 4];
      const float4 Bv0 = *(const float4*)&BS[n][t0];
      const float4 Bv1 = *(const float4*)&BS[n][t0 + 4];
      const float4 Cv0 = *(const float4*)&CS[n][t0];
      const float4 Cv1 = *(const float4*)&CS[n][t0 + 4];
      const float dt[8] = {dv0.x, dv0.y, dv0.z, dv0.w, dv1.x, dv1.y, dv1.z, dv1.w};
      const float xv[8] = {xv0.x, xv0.y, xv0.z, xv0.w, xv1.x, xv1.y, xv1.z, xv1.w};
      const float Bv[8] = {Bv0.x, Bv0.y, Bv0.z, Bv0.w, Bv1.x, Bv1.y, Bv1.z, Bv1.w};
      const float Cv[8] = {Cv0.x, Cv0.y, Cv0.z, Cv0.w, Cv1.x, Cv1.y, Cv1.z, Cv1.w};

      float e[8], u[8], p[8];
#pragma unroll
      for (int j = 0; j < 8; ++j) {       // independent: pipelines freely
        e[j] = exp2f(dt[j] * A2);         // single mul + v_exp (A2 pre-folded)
        u[j] = dt[j] * xv[j] * Bv[j];
      }
#pragma unroll
      for (int j = 0; j < 8; ++j) {       // the only true serial chain
        h = fmaf(e[j], h, u[j]);
        p[j] = h * Cv[j];
      }
#pragma unroll
      for (int j = 0; j < 8; ++j)         // 8 independent DPP chains
        p[j] = row16_reduce_add(p[j]);
      if (n == 15) {
#pragma unroll
        for (int j = 0; j < 8; ++j)
          yS[t0 + j][dc] = fmaf(Dd, xv[j], p[j]);
      }
    }
  }

  __syncthreads();
  {
    const int prow = rowbase + (NCH - 1) * TC + lt;
    float4 yv = *(const float4*)&yS[lt][lf];
    *(float4*)&out[(size_t)prow * DI + d0 + lf] = yv;
  }
}

// ---------------------------------------------------------------------------
extern "C" void kernel_launch(void* const* d_in, const int* in_sizes, int n_in,
                              void* d_out, int out_size, void* d_ws, size_t ws_size,
                              hipStream_t stream) {
  const float* x     = (const float*)d_in[0];  // (2,512,4096)
  const float* A_log = (const float*)d_in[1];  // (4096,16)
  const float* Dv    = (const float*)d_in[2];  // (4096,)
  const float* W     = (const float*)d_in[3];  // (160,4096)
  const float* dtw   = (const float*)d_in[4];  // (4096,128)
  const float* dtb   = (const float*)d_in[5];  // (4096,)
  float* out = (float*)d_out;

  // Workspace: xp fp32 accumulator [1024][160] = 655,360 B (L2-resident)
  float* xp = (float*)d_ws;

  zero_xp<<<dim3(160), 256, 0, stream>>>(xp);
  gemm_xp<<<dim3(64, KS), 256, 0, stream>>>(x, W, xp);
  scan_fused<<<dim3(512), 256, 0, stream>>>(x, A_log, Dv, xp, dtw, dtb, out);
}